// Round 10
// baseline (1230.119 us; speedup 1.0000x reference)
//
#include <hip/hip_runtime.h>
#include <math.h>

// ---------------- problem constants ----------------
constexpr int BB     = 4;
constexpr int WINN   = 10;
constexpr int NNODES = 10000;
constexpr int NFEAT  = 8;
constexpr int NHID   = 64;
constexpr int NTOT   = BB * WINN * NNODES;   // 400000 stacked nodes
constexpr int NEDGE  = 3200000;
constexpr int NBN    = BB * NNODES;          // 40000 sequences
constexpr float EPSBN = 1e-5f;

#define DEVFN static __device__ __forceinline__

typedef float f4 __attribute__((ext_vector_type(4)));
typedef short s8v __attribute__((ext_vector_type(8)));
typedef unsigned short ushort_t;
typedef unsigned int uint_t;

DEVFN float sigmoidf_(float x) { return 1.0f / (1.0f + __expf(-x)); }
DEVFN float tanhf_(float x) { return 2.0f / (1.0f + __expf(-2.0f * x)) - 1.0f; }
DEVFN ushort_t f2bf(float f) {             // round-to-nearest-even bf16
    uint_t x = __float_as_uint(f);
    return (ushort_t)((x + 0x7FFFu + ((x >> 16) & 1u)) >> 16);
}
DEVFN float bf2f(ushort_t u) { return __uint_as_float(((uint_t)u) << 16); }

// ---------------- diagnostic ----------------
__global__ void k_diag(float* out, float wsz, int n) {
    int i = blockIdx.x * 256 + threadIdx.x;
    if (i < n) out[i] = wsz;
}

// ---------------- init: zero partitioned histogram + BN sums ----------------
__global__ void k_init(int* cntP, float* sums) {
    int i = blockIdx.x * 256 + threadIdx.x;   // grid covers 8*NTOT
    if (i < 8 * NTOT) cntP[i] = 0;
    if (i < 2048) sums[i] = 0.f;
}

// partition-local histogram: cntP[blockIdx%8][col]++
__global__ void k_hist(const int* __restrict__ ei, int* __restrict__ cntP) {
    int e = blockIdx.x * 256 + threadIdx.x;
    int p = blockIdx.x & 7;
    if (e < NEDGE) atomicAdd(&cntP[p * NTOT + ei[NEDGE + e]], 1);
}

// ---------------- exclusive scan of per-node totals ----------------
__global__ void k_scan1(const int* __restrict__ cntP, int* __restrict__ ptr, int* __restrict__ tmp) {
    __shared__ int sdat[256];
    int tid = threadIdx.x;
    int base = blockIdx.x * 1024 + tid * 4;
    int v[4];
#pragma unroll
    for (int j = 0; j < 4; ++j) {
        int idx = base + j;
        int s = 0;
        if (idx < NTOT) {
#pragma unroll
            for (int p = 0; p < 8; ++p) s += cntP[p * NTOT + idx];
        }
        v[j] = s;
    }
    int sum = v[0] + v[1] + v[2] + v[3];
    sdat[tid] = sum;
    __syncthreads();
    for (int ofs = 1; ofs < 256; ofs <<= 1) {
        int x = (tid >= ofs) ? sdat[tid - ofs] : 0;
        __syncthreads();
        sdat[tid] += x;
        __syncthreads();
    }
    int run = sdat[tid] - sum;
    if (base + 0 < NTOT) ptr[base + 0] = run; run += v[0];
    if (base + 1 < NTOT) ptr[base + 1] = run; run += v[1];
    if (base + 2 < NTOT) ptr[base + 2] = run; run += v[2];
    if (base + 3 < NTOT) ptr[base + 3] = run;
    if (tid == 255) tmp[blockIdx.x] = sdat[255];
}

__global__ void k_scan2(int* tmp, int nb) {
    __shared__ int st[512];
    int tid = threadIdx.x;
    int v = (tid < nb) ? tmp[tid] : 0;
    st[tid] = v;
    __syncthreads();
    for (int ofs = 1; ofs < 512; ofs <<= 1) {
        int x = (tid >= ofs) ? st[tid - ofs] : 0;
        __syncthreads();
        st[tid] += x;
        __syncthreads();
    }
    if (tid < nb) tmp[tid] = st[tid] - v;
}

// finalize ptr; convert cntP in place to per-partition fill cursors
__global__ void k_scan3(int* __restrict__ ptr, int* __restrict__ cntP, const int* __restrict__ tmp) {
    int i = blockIdx.x * 256 + threadIdx.x;
    if (i < NTOT) {
        int p0 = ptr[i] + tmp[i >> 10];
        ptr[i] = p0;
        int run = p0;
#pragma unroll
        for (int p = 0; p < 8; ++p) {
            int c = cntP[p * NTOT + i];
            cntP[p * NTOT + i] = run;
            run += c;
        }
    }
    if (i == 0) ptr[NTOT] = NEDGE;
}

// CSR fill: epack[pos] = (row, ew), partition-local cursor atomics
__global__ void k_fill(const int* __restrict__ ei, const float* __restrict__ ew,
                       int* __restrict__ cur8, int2* __restrict__ epack) {
    int e = blockIdx.x * 256 + threadIdx.x;
    if (e >= NEDGE) return;
    int p = blockIdx.x & 7;
    int row = ei[e], col = ei[NEDGE + e];
    int pos = atomicAdd(&cur8[p * NTOT + col], 1);
    epack[pos] = make_int2(row, __float_as_int(ew[e]));
}

// dinv[node] = rsqrt(1 + sum(ew)) — coalesced, no atomics
__global__ void k_degcsr(const int* __restrict__ ptr, const int2* __restrict__ epack,
                         float* __restrict__ dinv) {
    int tid = threadIdx.x;
    int lane = tid & 63;
    int waveg = blockIdx.x * 4 + (tid >> 6);
    int g = lane >> 3, sub = lane & 7;
    int node = waveg * 8 + g;
    int beg = ptr[node], end = ptr[node + 1];
    float s = 0.f;
    for (int e = beg + sub; e < end; e += 8) s += __int_as_float(epack[e].y);
    s += __shfl_xor(s, 1, 64);
    s += __shfl_xor(s, 2, 64);
    s += __shfl_xor(s, 4, 64);
    if (sub == 0) dinv[node] = rsqrtf(1.0f + s);
}

// layer-1 gather over raw features (8 ch), norm inline, unroll-4
__global__ void k_gather8(const int* __restrict__ ptr, const int2* __restrict__ epack,
                          const float* __restrict__ x, const float* __restrict__ dinv,
                          float* __restrict__ aggX) {
    int tid = threadIdx.x;
    int lane = tid & 63;
    int waveg = blockIdx.x * 4 + (tid >> 6);
    int g = lane >> 3, ch = lane & 7;
    int node = waveg * 8 + g;
    int beg = ptr[node], end = ptr[node + 1];
    float dv = dinv[node];
    float accE = 0.f;
    int e = beg;
    for (; e + 3 < end; e += 4) {
        int2 p0 = epack[e], p1 = epack[e + 1], p2 = epack[e + 2], p3 = epack[e + 3];
        float n0 = dinv[p0.x] * __int_as_float(p0.y);
        float n1 = dinv[p1.x] * __int_as_float(p1.y);
        float n2 = dinv[p2.x] * __int_as_float(p2.y);
        float n3 = dinv[p3.x] * __int_as_float(p3.y);
        accE = fmaf(n0, x[p0.x * 8 + ch], accE);
        accE = fmaf(n1, x[p1.x * 8 + ch], accE);
        accE = fmaf(n2, x[p2.x * 8 + ch], accE);
        accE = fmaf(n3, x[p3.x * 8 + ch], accE);
    }
    for (; e < end; ++e) {
        int2 p = epack[e];
        accE = fmaf(dinv[p.x] * __int_as_float(p.y), x[p.x * 8 + ch], accE);
    }
    aggX[node * 8 + ch] = dv * fmaf(dv, x[node * 8 + ch], accE);
}

// rbf = bf16(relu(aggX @ W1 + b)) pre-BN + per-channel stats
__global__ void k_lin1(const float* __restrict__ aggX, const float* __restrict__ W,
                       const float* __restrict__ bias, ushort_t* __restrict__ rbf,
                       float* __restrict__ sums) {
    __shared__ float sW[NFEAT * NHID];
    int tid = threadIdx.x;
    sW[tid] = W[tid];
    sW[tid + 256] = W[tid + 256];
    __syncthreads();
    int c = tid & 63;
    float b = bias[c];
    float s = 0.f, sq = 0.f;
    int stride = gridDim.x * 256;
    for (int i = blockIdx.x * 256 + tid; i < NTOT * 64; i += stride) {
        int n = i >> 6;
        float acc = b;
#pragma unroll
        for (int f = 0; f < NFEAT; ++f) acc = fmaf(aggX[n * NFEAT + f], sW[f * NHID + c], acc);
        acc = acc > 0.f ? acc : 0.f;
        rbf[i] = f2bf(acc);
        s += acc;
        sq = fmaf(acc, acc, sq);
    }
    __shared__ float ls[4][64], lq[4][64];
    int w = tid >> 6;
    ls[w][c] = s; lq[w][c] = sq;
    __syncthreads();
    if (tid < 64) {
        atomicAdd(&sums[tid], ls[0][tid] + ls[1][tid] + ls[2][tid] + ls[3][tid]);
        atomicAdd(&sums[64 + tid], lq[0][tid] + lq[1][tid] + lq[2][tid] + lq[3][tid]);
    }
}

__global__ void k_bn_final(const float* __restrict__ sums, const float* __restrict__ g,
                           const float* __restrict__ b, float* __restrict__ ss) {
    int i = threadIdx.x;
    if (i >= 64) return;
    float mean = sums[i] * (1.0f / NTOT);
    float var = sums[64 + i] * (1.0f / NTOT) - mean * mean;
    float sc = g[i] * rsqrtf(var + EPSBN);
    ss[i] = sc;
    ss[64 + i] = b[i] - mean * sc;
}

__global__ void k_bn_final8(const float* __restrict__ sums8, const float* __restrict__ g,
                            const float* __restrict__ b, float* __restrict__ ss) {
    int i = threadIdx.x;
    if (i >= 64) return;
    float S = 0.f, Q = 0.f;
#pragma unroll
    for (int m = 0; m < 8; ++m) { S += sums8[m * 128 + i]; Q += sums8[m * 128 + 64 + i]; }
    float mean = S * (1.0f / NTOT);
    float var = Q * (1.0f / NTOT) - mean * mean;
    float sc = g[i] * rsqrtf(var + EPSBN);
    ss[i] = sc;
    ss[64 + i] = b[i] - mean * sc;
}

// fused GCN layer 2: gather(rbf) + inline BN1 (via sc,sh,S) + lin2 GEMV + relu + stats
__global__ void k_gcn2(const int* __restrict__ ptr, const int2* __restrict__ epack,
                       const ushort_t* __restrict__ rbf, const float* __restrict__ dinv,
                       const float* __restrict__ ss1, const float* __restrict__ W2,
                       const float* __restrict__ bias2, ushort_t* __restrict__ h2bf,
                       float* __restrict__ sums8) {
    __shared__ __align__(16) float srow[4][64];
    __shared__ float ls[4][64], lq[4][64];
    int lane = threadIdx.x & 63, wv = threadIdx.x >> 6;
    float wc[64];
#pragma unroll
    for (int h = 0; h < 64; ++h) wc[h] = W2[h * 64 + lane];
    float b2v = bias2[lane];
    float sc1 = ss1[lane], sh1 = ss1[64 + lane];
    float s = 0.f, sq = 0.f;
    int wid = blockIdx.x * 4 + wv;
    int nw = gridDim.x * 4;
    for (int node = wid; node < NTOT; node += nw) {
        int beg = ptr[node], end = ptr[node + 1];
        float dv = dinv[node];
        float accE = 0.f, accS = 0.f;
        int e = beg;
        for (; e + 3 < end; e += 4) {
            int2 p0 = epack[e], p1 = epack[e + 1], p2 = epack[e + 2], p3 = epack[e + 3];
            float n0 = dinv[p0.x] * __int_as_float(p0.y);
            float n1 = dinv[p1.x] * __int_as_float(p1.y);
            float n2 = dinv[p2.x] * __int_as_float(p2.y);
            float n3 = dinv[p3.x] * __int_as_float(p3.y);
            accE = fmaf(n0, bf2f(rbf[(size_t)p0.x * 64 + lane]), accE);
            accE = fmaf(n1, bf2f(rbf[(size_t)p1.x * 64 + lane]), accE);
            accE = fmaf(n2, bf2f(rbf[(size_t)p2.x * 64 + lane]), accE);
            accE = fmaf(n3, bf2f(rbf[(size_t)p3.x * 64 + lane]), accE);
            accS += n0 + n1 + n2 + n3;
        }
        for (; e < end; ++e) {
            int2 p = epack[e];
            float nv = dinv[p.x] * __int_as_float(p.y);
            accE = fmaf(nv, bf2f(rbf[(size_t)p.x * 64 + lane]), accE);
            accS += nv;
        }
        float G = dv * fmaf(dv, bf2f(rbf[(size_t)node * 64 + lane]), accE);
        float S = dv * (dv + accS);
        srow[wv][lane] = fmaf(sc1, G, sh1 * S);   // post-BN1 aggregate
        float acc = b2v;                          // same-wave LDS write->read (lgkmcnt)
#pragma unroll
        for (int h4 = 0; h4 < 16; ++h4) {
            float4 iv = *reinterpret_cast<const float4*>(&srow[wv][h4 * 4]);
            acc = fmaf(iv.x, wc[h4 * 4 + 0], acc);
            acc = fmaf(iv.y, wc[h4 * 4 + 1], acc);
            acc = fmaf(iv.z, wc[h4 * 4 + 2], acc);
            acc = fmaf(iv.w, wc[h4 * 4 + 3], acc);
        }
        acc = acc > 0.f ? acc : 0.f;
        h2bf[(size_t)node * 64 + lane] = f2bf(acc);
        s += acc;
        sq = fmaf(acc, acc, sq);
    }
    ls[wv][lane] = s; lq[wv][lane] = sq;
    __syncthreads();
    if (threadIdx.x < 64) {
        float S_ = ls[0][lane] + ls[1][lane] + ls[2][lane] + ls[3][lane];
        float Q_ = lq[0][lane] + lq[1][lane] + lq[2][lane] + lq[3][lane];
        float* d = sums8 + (blockIdx.x & 7) * 128;
        atomicAdd(&d[lane], S_);
        atomicAdd(&d[64 + lane], Q_);
    }
}

// build MFMA-layout weights: wB1f fp32 [256][192]; wB2h bf16 [256][128]; biases; fc1T
__global__ void k_prep(const float* __restrict__ wih1, const float* __restrict__ whh1,
                       const float* __restrict__ bih1, const float* __restrict__ bhh1,
                       const float* __restrict__ wih2, const float* __restrict__ whh2,
                       const float* __restrict__ bih2, const float* __restrict__ bhh2,
                       const float* __restrict__ fc1w,
                       float* wB1f, float* b1, ushort_t* wB2h, float* b2, float* fc1T) {
    int i = blockIdx.x * 256 + threadIdx.x;
    if (i < 256 * 192) {
        int n = i / 192, k = i - n * 192;
        wB1f[i] = (k < 128) ? wih1[n * 128 + k] : whh1[n * 64 + (k - 128)];
    }
    if (i < 256 * 128) {
        int n = i >> 7, k = i & 127;
        wB2h[i] = f2bf((k < 64) ? wih2[n * 64 + k] : whh2[n * 64 + (k - 64)]);
    }
    if (i < 208 * 64) {
        int k = i >> 6, o = i & 63;
        fc1T[i] = fc1w[o * 208 + k];
    }
    if (i < 256) { b1[i] = bih1[i] + bhh1[i]; b2[i] = bih2[i] + bhh2[i]; }
}

// fold BN1 (cols 0..63) and BN2 (cols 64..127) into wB1 + b1; convert -> bf16
__global__ void k_fold2(float* __restrict__ wB1f, float* __restrict__ b1,
                        const float* __restrict__ ss1, const float* __restrict__ ss2,
                        ushort_t* __restrict__ wB1h) {
    int n = threadIdx.x;   // 256 gate outputs
    float acc = 0.f;
#pragma unroll
    for (int m = 0; m < 64; ++m) {
        float w = wB1f[n * 192 + m];
        acc = fmaf(w, ss1[64 + m], acc);
        wB1f[n * 192 + m] = w * ss1[m];
    }
#pragma unroll
    for (int m = 0; m < 64; ++m) {
        float w = wB1f[n * 192 + 64 + m];
        acc = fmaf(w, ss2[64 + m], acc);
        wB1f[n * 192 + 64 + m] = w * ss2[m];
    }
    b1[n] += acc;
    __syncthreads();
    for (int j = n; j < 256 * 192; j += 256) wB1h[j] = f2bf(wB1f[j]);
}

// ---------------- MFMA 2-layer LSTM: 4 waves, weights in regs, 2 barriers/t ----------------
__global__ __launch_bounds__(256, 2) void k_lstm_mfma4(
    const ushort_t* __restrict__ h1bf, const ushort_t* __restrict__ h2bf,
    const ushort_t* __restrict__ wB1, const ushort_t* __restrict__ wB2,
    const float* __restrict__ bs1, const float* __restrict__ bs2,
    float* __restrict__ hA, float* __restrict__ hB) {
    __shared__ ushort_t hx1[1024];          // layer-1 h state, XOR-swizzled
    __shared__ ushort_t hx2[2][1024];       // layer-2 h state, t-parity double buffer
    int tid = threadIdx.x;
    int lane = tid & 63, wv = tid >> 6;
    int c15 = lane & 15, g4 = lane >> 4;
    int g8 = g4 * 8;
    int bn0 = blockIdx.x * 16;
    int b = bn0 / NNODES, nn0 = bn0 - b * NNODES;

    for (int i = tid; i < 1536; i += 256) {
        if (i < 512) ((uint_t*)hx1)[i] = 0u;
        else ((uint_t*)hx2)[i - 512] = 0u;
    }

    s8v w1f[4][6], w2f[4][4];
#pragma unroll
    for (int j = 0; j < 4; ++j) {
        const ushort_t* base1 = wB1 + (size_t)((wv + 4 * j) * 16 + c15) * 192 + g8;
#pragma unroll
        for (int kk = 0; kk < 6; ++kk) w1f[j][kk] = *(const s8v*)(base1 + kk * 32);
        const ushort_t* base2 = wB2 + (size_t)((wv + 4 * j) * 16 + c15) * 128 + g8;
#pragma unroll
        for (int kk = 0; kk < 4; ++kk) w2f[j][kk] = *(const s8v*)(base2 + kk * 32);
    }
    float bi1[4], bi2[4];
#pragma unroll
    for (int j = 0; j < 4; ++j) {
        bi1[j] = bs1[(wv + 4 * j) * 16 + c15];
        bi2[j] = bs2[(wv + 4 * j) * 16 + c15];
    }
    float cA[4], cB[4];
#pragma unroll
    for (int q = 0; q < 4; ++q) { cA[q] = 0.f; cB[q] = 0.f; }

    int r7 = c15 & 7;
    int a_lo = c15 * 64 + ((g4 ^ r7) << 3);
    int a_hi = c15 * 64 + (((4 + g4) ^ r7) << 3);
    int u = wv * 16 + c15;
    int hxcol_hi = (u >> 3) << 3;
    int u7 = u & 7;

    __syncthreads();

    for (int t = 0; t < WINN; ++t) {
        size_t node = (size_t)((b * WINN + t) * NNODES + nn0 + c15) * 64 + g8;
        s8v a[6];
        a[0] = *(const s8v*)(h1bf + node);
        a[1] = *(const s8v*)(h1bf + node + 32);
        a[2] = *(const s8v*)(h2bf + node);
        a[3] = *(const s8v*)(h2bf + node + 32);
        a[4] = *(const s8v*)(&hx1[a_lo]);
        a[5] = *(const s8v*)(&hx1[a_hi]);

        f4 acc[4];
#pragma unroll
        for (int j = 0; j < 4; ++j) { f4 v = {bi1[j], bi1[j], bi1[j], bi1[j]}; acc[j] = v; }
#pragma unroll
        for (int j = 0; j < 4; ++j)
#pragma unroll
            for (int kk = 0; kk < 6; ++kk)
                acc[j] = __builtin_amdgcn_mfma_f32_16x16x32_bf16(a[kk], w1f[j][kk], acc[j], 0, 0, 0);
        __syncthreads();   // B1: all waves done reading hx1(prev)
#pragma unroll
        for (int q = 0; q < 4; ++q) {
            float ig = sigmoidf_(acc[0][q]);
            float fg = sigmoidf_(acc[1][q]);
            float gg = tanhf_(acc[2][q]);
            float og = sigmoidf_(acc[3][q]);
            float cv = fmaf(fg, cA[q], ig * gg);
            cA[q] = cv;
            float hv = og * tanhf_(cv);
            int rr = g4 * 4 + q;
            hx1[rr * 64 + (hxcol_hi ^ ((rr & 7) << 3)) + u7] = f2bf(hv);
        }
        __syncthreads();   // B2: hx1(new) visible

        const ushort_t* hp = hx2[1 - (t & 1)];
        s8v r[4];
        r[0] = *(const s8v*)(&hx1[a_lo]);
        r[1] = *(const s8v*)(&hx1[a_hi]);
        r[2] = *(const s8v*)(&hp[a_lo]);
        r[3] = *(const s8v*)(&hp[a_hi]);
#pragma unroll
        for (int j = 0; j < 4; ++j) { f4 v = {bi2[j], bi2[j], bi2[j], bi2[j]}; acc[j] = v; }
#pragma unroll
        for (int j = 0; j < 4; ++j)
#pragma unroll
            for (int kk = 0; kk < 4; ++kk)
                acc[j] = __builtin_amdgcn_mfma_f32_16x16x32_bf16(r[kk], w2f[j][kk], acc[j], 0, 0, 0);
        ushort_t* hw = hx2[t & 1];   // write alternate buffer: no WAR barrier needed
#pragma unroll
        for (int q = 0; q < 4; ++q) {
            float ig = sigmoidf_(acc[0][q]);
            float fg = sigmoidf_(acc[1][q]);
            float gg = tanhf_(acc[2][q]);
            float og = sigmoidf_(acc[3][q]);
            float cv = fmaf(fg, cB[q], ig * gg);
            cB[q] = cv;
            float hv = og * tanhf_(cv);
            int rr = g4 * 4 + q;
            hw[rr * 64 + (hxcol_hi ^ ((rr & 7) << 3)) + u7] = f2bf(hv);
        }
        // visibility of hx2(new) for next t covered by next iteration's B1/B2
    }
    __syncthreads();
    const ushort_t* hf = hx2[(WINN - 1) & 1];
    for (int i = tid; i < 1024; i += 256) {
        int rr = i >> 6, uu = i & 63;
        int hw2 = rr * 64 + ((((uu >> 3) ^ (rr & 7)) << 3)) + (uu & 7);
        hA[(size_t)(bn0 + rr) * 64 + uu] = bf2f(hx1[hw2]);
        hB[(size_t)(bn0 + rr) * 64 + uu] = bf2f(hf[hw2]);
    }
}

// head: z = relu([hn1|hn2|skip] @ fc1^T + b1); out = relu(z @ fc2^T + b2)
__global__ void k_head(const float* __restrict__ hA, const float* __restrict__ hB,
                       const float* __restrict__ x, const float* __restrict__ fc1T,
                       const float* __restrict__ fc1b, const float* __restrict__ fc2w,
                       const float* __restrict__ fc2b, float* __restrict__ out) {
    int lane = threadIdx.x & 63, wv = threadIdx.x >> 6;
    int bn = blockIdx.x * 4 + wv;
    __shared__ float sz[4][208];
    int b = bn / NNODES, nn = bn - b * NNODES;
    for (int k = lane; k < 208; k += 64) {
        float v;
        if (k < 64) v = hA[(size_t)bn * 64 + k];
        else if (k < 128) v = hB[(size_t)bn * 64 + (k - 64)];
        else {
            int kk = k - 128;
            int w = kk >> 3, f = kk & 7;
            v = x[(size_t)((b * WINN + w) * NNODES + nn) * NFEAT + f];
        }
        sz[wv][k] = v;
    }
    __syncthreads();
    float acc = fc1b[lane];
    for (int k = 0; k < 208; ++k) acc = fmaf(sz[wv][k], fc1T[k * 64 + lane], acc);
    acc = acc > 0.f ? acc : 0.f;
    float v = acc * fc2w[lane];
#pragma unroll
    for (int m = 32; m >= 1; m >>= 1) v += __shfl_xor(v, m, 64);
    if (lane == 0) {
        float z = v + fc2b[0];
        out[bn] = z > 0.f ? z : 0.f;
    }
}

// ---------------- launch ----------------
extern "C" void kernel_launch(void* const* d_in, const int* in_sizes, int n_in,
                              void* d_out, int out_size, void* d_ws, size_t ws_size,
                              hipStream_t stream) {
    const float* x     = (const float*)d_in[0];
    const int*   ei    = (const int*)d_in[1];
    const float* ew    = (const float*)d_in[2];
    const float* c1w   = (const float*)d_in[3];
    const float* c1b   = (const float*)d_in[4];
    const float* c2w   = (const float*)d_in[5];
    const float* c2b   = (const float*)d_in[6];
    const float* bn1g  = (const float*)d_in[7];
    const float* bn1b  = (const float*)d_in[8];
    const float* bn2g  = (const float*)d_in[9];
    const float* bn2b  = (const float*)d_in[10];
    const float* wih1  = (const float*)d_in[11];
    const float* whh1  = (const float*)d_in[12];
    const float* bih1  = (const float*)d_in[13];
    const float* bhh1  = (const float*)d_in[14];
    const float* wih2  = (const float*)d_in[15];
    const float* whh2  = (const float*)d_in[16];
    const float* bih2  = (const float*)d_in[17];
    const float* bhh2  = (const float*)d_in[18];
    const float* fc1w  = (const float*)d_in[19];
    const float* fc1b  = (const float*)d_in[20];
    const float* fc2w  = (const float*)d_in[21];
    const float* fc2b  = (const float*)d_in[22];
    float* out = (float*)d_out;

    float* ws = (float*)d_ws;
    size_t off = 0;
    auto A = [&](size_t n) { float* p = ws + off; off += n; return p; };
    float* dinv   = A(NTOT);
    float* aggX   = A((size_t)NTOT * NFEAT);
    ushort_t* h1bf = (ushort_t*)A((size_t)NTOT * 32);   // r = relu(gcn1), pre-BN, bf16
    ushort_t* h2bf = (ushort_t*)A((size_t)NTOT * 32);   // relu(gcn2), pre-BN2, bf16

    // union: CSR (GCN phase) aliases final LSTM states (LSTM/head phase)
    size_t uoff = off;
    float* hA = A((size_t)NBN * 64);
    float* hB = A((size_t)NBN * 64);
    A(2 * (size_t)NEDGE + (NTOT + 1) + 8 * (size_t)NTOT - 2 * (size_t)NBN * 64);
    int2* epack = (int2*)(ws + uoff);
    int*  ptr   = (int*)(epack + NEDGE);        // NTOT+1
    int*  cntP  = ptr + NTOT + 1;               // 8*NTOT (hist, then cursors)

    float* wB1f = A(256 * 192);
    ushort_t* wB1h = (ushort_t*)A(256 * 96);
    ushort_t* wB2h = (ushort_t*)A(256 * 64);
    float* b1   = A(256);
    float* b2   = A(256);
    float* fc1T = A(208 * 64);
    float* sums = A(2048);
    float* ss1  = A(128);
    float* ss2  = A(128);
    float* scanTmpF = A(512);
    int* scanTmp = (int*)scanTmpF;
    // total ~39.3M floats = 157 MB

    if (ws_size < off * sizeof(float)) {
        k_diag<<<(out_size + 255) / 256, 256, 0, stream>>>(out, (float)ws_size, out_size);
        return;
    }

    constexpr int SCAN_NB = (NTOT + 1023) / 1024;

    // CSR build
    k_init<<<8 * NTOT / 256, 256, 0, stream>>>(cntP, sums);
    k_hist<<<NEDGE / 256, 256, 0, stream>>>(ei, cntP);
    k_scan1<<<SCAN_NB, 256, 0, stream>>>(cntP, ptr, scanTmp);
    k_scan2<<<1, 512, 0, stream>>>(scanTmp, SCAN_NB);
    k_scan3<<<(NTOT + 255) / 256, 256, 0, stream>>>(ptr, cntP, scanTmp);
    k_fill<<<NEDGE / 256, 256, 0, stream>>>(ei, ew, cntP, epack);
    k_degcsr<<<NTOT / 8 / 4, 256, 0, stream>>>(ptr, epack, dinv);
    k_prep<<<192, 256, 0, stream>>>(wih1, whh1, bih1, bhh1, wih2, whh2, bih2, bhh2,
                                    fc1w, wB1f, b1, wB2h, b2, fc1T);

    // ---- GCN layer 1 (BN1 never materialized: stats only) ----
    k_gather8<<<NTOT / 8 / 4, 256, 0, stream>>>(ptr, epack, x, dinv, aggX);
    k_lin1<<<512, 256, 0, stream>>>(aggX, c1w, c1b, h1bf, sums);
    k_bn_final<<<1, 64, 0, stream>>>(sums, bn1g, bn1b, ss1);

    // ---- GCN layer 2 fused: gather + inline-BN1 + lin2 + relu + stats ----
    k_gcn2<<<2048, 256, 0, stream>>>(ptr, epack, h1bf, dinv, ss1, c2w, c2b, h2bf, sums + 128);
    k_bn_final8<<<1, 64, 0, stream>>>(sums + 128, bn2g, bn2b, ss2);
    k_fold2<<<1, 256, 0, stream>>>(wB1f, b1, ss1, ss2, wB1h);

    // ---- MFMA LSTM: weights in VGPRs, 2 barriers/t ----
    k_lstm_mfma4<<<NBN / 16, 256, 0, stream>>>(h1bf, h2bf, wB1h, wB2h, b1, b2, hA, hB);

    // ---- head ----
    k_head<<<NBN / 4, 256, 0, stream>>>(hA, hB, x, fc1T, fc1b, fc2w, fc2b, out);
}

// Round 11
// 1077.359 us; speedup vs baseline: 1.1418x; 1.1418x over previous
//
#include <hip/hip_runtime.h>
#include <math.h>

// ---------------- problem constants ----------------
constexpr int BB     = 4;
constexpr int WINN   = 10;
constexpr int NNODES = 10000;
constexpr int NFEAT  = 8;
constexpr int NHID   = 64;
constexpr int NTOT   = BB * WINN * NNODES;   // 400000 stacked nodes
constexpr int NEDGE  = 3200000;
constexpr int NBN    = BB * NNODES;          // 40000 sequences
constexpr float EPSBN = 1e-5f;

#define DEVFN static __device__ __forceinline__

typedef float f4 __attribute__((ext_vector_type(4)));
typedef short s8v __attribute__((ext_vector_type(8)));
typedef unsigned short ushort_t;
typedef unsigned int uint_t;

DEVFN float sigmoidf_(float x) { return 1.0f / (1.0f + __expf(-x)); }
DEVFN float tanhf_(float x) { return 2.0f / (1.0f + __expf(-2.0f * x)) - 1.0f; }
DEVFN ushort_t f2bf(float f) {             // round-to-nearest-even bf16
    uint_t x = __float_as_uint(f);
    return (ushort_t)((x + 0x7FFFu + ((x >> 16) & 1u)) >> 16);
}
DEVFN float bf2f(ushort_t u) { return __uint_as_float(((uint_t)u) << 16); }

// ---------------- diagnostic ----------------
__global__ void k_diag(float* out, float wsz, int n) {
    int i = blockIdx.x * 256 + threadIdx.x;
    if (i < n) out[i] = wsz;
}

// ---------------- init: zero partitioned histogram + BN sums ----------------
__global__ void k_init(int* cntP, float* sums) {
    int i = blockIdx.x * 256 + threadIdx.x;   // grid covers 8*NTOT
    if (i < 8 * NTOT) cntP[i] = 0;
    if (i < 2048) sums[i] = 0.f;
}

// partition-local histogram: cntP[blockIdx%8][col]++
__global__ void k_hist(const int* __restrict__ ei, int* __restrict__ cntP) {
    int e = blockIdx.x * 256 + threadIdx.x;
    int p = blockIdx.x & 7;
    if (e < NEDGE) atomicAdd(&cntP[p * NTOT + ei[NEDGE + e]], 1);
}

// ---------------- exclusive scan of per-node totals ----------------
__global__ void k_scan1(const int* __restrict__ cntP, int* __restrict__ ptr, int* __restrict__ tmp) {
    __shared__ int sdat[256];
    int tid = threadIdx.x;
    int base = blockIdx.x * 1024 + tid * 4;
    int v[4];
#pragma unroll
    for (int j = 0; j < 4; ++j) {
        int idx = base + j;
        int s = 0;
        if (idx < NTOT) {
#pragma unroll
            for (int p = 0; p < 8; ++p) s += cntP[p * NTOT + idx];
        }
        v[j] = s;
    }
    int sum = v[0] + v[1] + v[2] + v[3];
    sdat[tid] = sum;
    __syncthreads();
    for (int ofs = 1; ofs < 256; ofs <<= 1) {
        int x = (tid >= ofs) ? sdat[tid - ofs] : 0;
        __syncthreads();
        sdat[tid] += x;
        __syncthreads();
    }
    int run = sdat[tid] - sum;
    if (base + 0 < NTOT) ptr[base + 0] = run; run += v[0];
    if (base + 1 < NTOT) ptr[base + 1] = run; run += v[1];
    if (base + 2 < NTOT) ptr[base + 2] = run; run += v[2];
    if (base + 3 < NTOT) ptr[base + 3] = run;
    if (tid == 255) tmp[blockIdx.x] = sdat[255];
}

__global__ void k_scan2(int* tmp, int nb) {
    __shared__ int st[512];
    int tid = threadIdx.x;
    int v = (tid < nb) ? tmp[tid] : 0;
    st[tid] = v;
    __syncthreads();
    for (int ofs = 1; ofs < 512; ofs <<= 1) {
        int x = (tid >= ofs) ? st[tid - ofs] : 0;
        __syncthreads();
        st[tid] += x;
        __syncthreads();
    }
    if (tid < nb) tmp[tid] = st[tid] - v;
}

// finalize ptr; convert cntP in place to per-partition fill cursors
__global__ void k_scan3(int* __restrict__ ptr, int* __restrict__ cntP, const int* __restrict__ tmp) {
    int i = blockIdx.x * 256 + threadIdx.x;
    if (i < NTOT) {
        int p0 = ptr[i] + tmp[i >> 10];
        ptr[i] = p0;
        int run = p0;
#pragma unroll
        for (int p = 0; p < 8; ++p) {
            int c = cntP[p * NTOT + i];
            cntP[p * NTOT + i] = run;
            run += c;
        }
    }
    if (i == 0) ptr[NTOT] = NEDGE;
}

// CSR fill: epack[pos] = (row, ew), partition-local cursor atomics
__global__ void k_fill(const int* __restrict__ ei, const float* __restrict__ ew,
                       int* __restrict__ cur8, int2* __restrict__ epack) {
    int e = blockIdx.x * 256 + threadIdx.x;
    if (e >= NEDGE) return;
    int p = blockIdx.x & 7;
    int row = ei[e], col = ei[NEDGE + e];
    int pos = atomicAdd(&cur8[p * NTOT + col], 1);
    epack[pos] = make_int2(row, __float_as_int(ew[e]));
}

// dinv[node] = rsqrt(1 + sum(ew)) — coalesced, no atomics
__global__ void k_degcsr(const int* __restrict__ ptr, const int2* __restrict__ epack,
                         float* __restrict__ dinv) {
    int tid = threadIdx.x;
    int lane = tid & 63;
    int waveg = blockIdx.x * 4 + (tid >> 6);
    int g = lane >> 3, sub = lane & 7;
    int node = waveg * 8 + g;
    int beg = ptr[node], end = ptr[node + 1];
    float s = 0.f;
    for (int e = beg + sub; e < end; e += 8) s += __int_as_float(epack[e].y);
    s += __shfl_xor(s, 1, 64);
    s += __shfl_xor(s, 2, 64);
    s += __shfl_xor(s, 4, 64);
    if (sub == 0) dinv[node] = rsqrtf(1.0f + s);
}

// layer-1 gather over raw features (8 ch), norm inline, unroll-4
__global__ void k_gather8(const int* __restrict__ ptr, const int2* __restrict__ epack,
                          const float* __restrict__ x, const float* __restrict__ dinv,
                          float* __restrict__ aggX) {
    int tid = threadIdx.x;
    int lane = tid & 63;
    int waveg = blockIdx.x * 4 + (tid >> 6);
    int g = lane >> 3, ch = lane & 7;
    int node = waveg * 8 + g;
    int beg = ptr[node], end = ptr[node + 1];
    float dv = dinv[node];
    float accE = 0.f;
    int e = beg;
    for (; e + 3 < end; e += 4) {
        int2 p0 = epack[e], p1 = epack[e + 1], p2 = epack[e + 2], p3 = epack[e + 3];
        float n0 = dinv[p0.x] * __int_as_float(p0.y);
        float n1 = dinv[p1.x] * __int_as_float(p1.y);
        float n2 = dinv[p2.x] * __int_as_float(p2.y);
        float n3 = dinv[p3.x] * __int_as_float(p3.y);
        accE = fmaf(n0, x[p0.x * 8 + ch], accE);
        accE = fmaf(n1, x[p1.x * 8 + ch], accE);
        accE = fmaf(n2, x[p2.x * 8 + ch], accE);
        accE = fmaf(n3, x[p3.x * 8 + ch], accE);
    }
    for (; e < end; ++e) {
        int2 p = epack[e];
        accE = fmaf(dinv[p.x] * __int_as_float(p.y), x[p.x * 8 + ch], accE);
    }
    aggX[node * 8 + ch] = dv * fmaf(dv, x[node * 8 + ch], accE);
}

// rbf = bf16(relu(aggX @ W1 + b)) pre-BN + per-channel stats
__global__ void k_lin1(const float* __restrict__ aggX, const float* __restrict__ W,
                       const float* __restrict__ bias, ushort_t* __restrict__ rbf,
                       float* __restrict__ sums) {
    __shared__ float sW[NFEAT * NHID];
    int tid = threadIdx.x;
    sW[tid] = W[tid];
    sW[tid + 256] = W[tid + 256];
    __syncthreads();
    int c = tid & 63;
    float b = bias[c];
    float s = 0.f, sq = 0.f;
    int stride = gridDim.x * 256;
    for (int i = blockIdx.x * 256 + tid; i < NTOT * 64; i += stride) {
        int n = i >> 6;
        float acc = b;
#pragma unroll
        for (int f = 0; f < NFEAT; ++f) acc = fmaf(aggX[n * NFEAT + f], sW[f * NHID + c], acc);
        acc = acc > 0.f ? acc : 0.f;
        rbf[i] = f2bf(acc);
        s += acc;
        sq = fmaf(acc, acc, sq);
    }
    __shared__ float ls[4][64], lq[4][64];
    int w = tid >> 6;
    ls[w][c] = s; lq[w][c] = sq;
    __syncthreads();
    if (tid < 64) {
        atomicAdd(&sums[tid], ls[0][tid] + ls[1][tid] + ls[2][tid] + ls[3][tid]);
        atomicAdd(&sums[64 + tid], lq[0][tid] + lq[1][tid] + lq[2][tid] + lq[3][tid]);
    }
}

__global__ void k_bn_final(const float* __restrict__ sums, const float* __restrict__ g,
                           const float* __restrict__ b, float* __restrict__ ss) {
    int i = threadIdx.x;
    if (i >= 64) return;
    float mean = sums[i] * (1.0f / NTOT);
    float var = sums[64 + i] * (1.0f / NTOT) - mean * mean;
    float sc = g[i] * rsqrtf(var + EPSBN);
    ss[i] = sc;
    ss[64 + i] = b[i] - mean * sc;
}

__global__ void k_bn_final8(const float* __restrict__ sums8, const float* __restrict__ g,
                            const float* __restrict__ b, float* __restrict__ ss) {
    int i = threadIdx.x;
    if (i >= 64) return;
    float S = 0.f, Q = 0.f;
#pragma unroll
    for (int m = 0; m < 8; ++m) { S += sums8[m * 128 + i]; Q += sums8[m * 128 + 64 + i]; }
    float mean = S * (1.0f / NTOT);
    float var = Q * (1.0f / NTOT) - mean * mean;
    float sc = g[i] * rsqrtf(var + EPSBN);
    ss[i] = sc;
    ss[64 + i] = b[i] - mean * sc;
}

// layer-2 gather: one wave per node (max TLP), BN1 applied inline, writes bf16 aggregate
__global__ void k_gather64b(const int* __restrict__ ptr, const int2* __restrict__ epack,
                            const ushort_t* __restrict__ rbf, const float* __restrict__ dinv,
                            const float* __restrict__ ss1, ushort_t* __restrict__ gout) {
    int lane = threadIdx.x & 63;
    int node = blockIdx.x * 4 + (threadIdx.x >> 6);   // grid exact: NTOT/4 blocks
    int beg = ptr[node], end = ptr[node + 1];
    float dv = dinv[node];
    float accE = 0.f, accS = 0.f;
    int e = beg;
    for (; e + 3 < end; e += 4) {
        int2 p0 = epack[e], p1 = epack[e + 1], p2 = epack[e + 2], p3 = epack[e + 3];
        float n0 = dinv[p0.x] * __int_as_float(p0.y);
        float n1 = dinv[p1.x] * __int_as_float(p1.y);
        float n2 = dinv[p2.x] * __int_as_float(p2.y);
        float n3 = dinv[p3.x] * __int_as_float(p3.y);
        accE = fmaf(n0, bf2f(rbf[(size_t)p0.x * 64 + lane]), accE);
        accE = fmaf(n1, bf2f(rbf[(size_t)p1.x * 64 + lane]), accE);
        accE = fmaf(n2, bf2f(rbf[(size_t)p2.x * 64 + lane]), accE);
        accE = fmaf(n3, bf2f(rbf[(size_t)p3.x * 64 + lane]), accE);
        accS += n0 + n1 + n2 + n3;
    }
    for (; e < end; ++e) {
        int2 p = epack[e];
        float nv = dinv[p.x] * __int_as_float(p.y);
        accE = fmaf(nv, bf2f(rbf[(size_t)p.x * 64 + lane]), accE);
        accS += nv;
    }
    float G = dv * fmaf(dv, bf2f(rbf[(size_t)node * 64 + lane]), accE);
    float S = dv * (dv + accS);
    gout[(size_t)node * 64 + lane] = f2bf(fmaf(ss1[lane], G, ss1[64 + lane] * S));
}

// lin2: h2bf = bf16(relu(gout @ W2 + b)) + stats; W2 cols in registers, grid-stride
__global__ void k_lin2c(const ushort_t* __restrict__ gin, const float* __restrict__ W2,
                        const float* __restrict__ bias, ushort_t* __restrict__ dst,
                        float* __restrict__ sums8) {
    __shared__ __align__(16) float srow[4][64];
    __shared__ float ls[4][64], lq[4][64];
    int lane = threadIdx.x & 63, wv = threadIdx.x >> 6;
    float wc[64];
#pragma unroll
    for (int h = 0; h < 64; ++h) wc[h] = W2[h * 64 + lane];
    float b = bias[lane];
    float s = 0.f, sq = 0.f;
    int wid = blockIdx.x * 4 + wv;
    int nw = gridDim.x * 4;
    for (int row = wid; row < NTOT; row += nw) {
        srow[wv][lane] = bf2f(gin[(size_t)row * 64 + lane]);   // coalesced 128B -> LDS
        float acc = b;                                          // same-wave write->read
#pragma unroll
        for (int h4 = 0; h4 < 16; ++h4) {
            float4 iv = *reinterpret_cast<const float4*>(&srow[wv][h4 * 4]);
            acc = fmaf(iv.x, wc[h4 * 4 + 0], acc);
            acc = fmaf(iv.y, wc[h4 * 4 + 1], acc);
            acc = fmaf(iv.z, wc[h4 * 4 + 2], acc);
            acc = fmaf(iv.w, wc[h4 * 4 + 3], acc);
        }
        acc = acc > 0.f ? acc : 0.f;
        dst[(size_t)row * 64 + lane] = f2bf(acc);
        s += acc;
        sq = fmaf(acc, acc, sq);
    }
    ls[wv][lane] = s; lq[wv][lane] = sq;
    __syncthreads();
    if (threadIdx.x < 64) {
        float S = ls[0][lane] + ls[1][lane] + ls[2][lane] + ls[3][lane];
        float Q = lq[0][lane] + lq[1][lane] + lq[2][lane] + lq[3][lane];
        float* d = sums8 + (blockIdx.x & 7) * 128;
        atomicAdd(&d[lane], S);
        atomicAdd(&d[64 + lane], Q);
    }
}

// build MFMA-layout weights: wB1f fp32 [256][192]; wB2h bf16 [256][128]; biases; fc1T
__global__ void k_prep(const float* __restrict__ wih1, const float* __restrict__ whh1,
                       const float* __restrict__ bih1, const float* __restrict__ bhh1,
                       const float* __restrict__ wih2, const float* __restrict__ whh2,
                       const float* __restrict__ bih2, const float* __restrict__ bhh2,
                       const float* __restrict__ fc1w,
                       float* wB1f, float* b1, ushort_t* wB2h, float* b2, float* fc1T) {
    int i = blockIdx.x * 256 + threadIdx.x;
    if (i < 256 * 192) {
        int n = i / 192, k = i - n * 192;
        wB1f[i] = (k < 128) ? wih1[n * 128 + k] : whh1[n * 64 + (k - 128)];
    }
    if (i < 256 * 128) {
        int n = i >> 7, k = i & 127;
        wB2h[i] = f2bf((k < 64) ? wih2[n * 64 + k] : whh2[n * 64 + (k - 64)]);
    }
    if (i < 208 * 64) {
        int k = i >> 6, o = i & 63;
        fc1T[i] = fc1w[o * 208 + k];
    }
    if (i < 256) { b1[i] = bih1[i] + bhh1[i]; b2[i] = bih2[i] + bhh2[i]; }
}

// fold BN1 (cols 0..63) and BN2 (cols 64..127) into wB1 + b1; convert -> bf16
__global__ void k_fold2(float* __restrict__ wB1f, float* __restrict__ b1,
                        const float* __restrict__ ss1, const float* __restrict__ ss2,
                        ushort_t* __restrict__ wB1h) {
    int n = threadIdx.x;   // 256 gate outputs
    float acc = 0.f;
#pragma unroll
    for (int m = 0; m < 64; ++m) {
        float w = wB1f[n * 192 + m];
        acc = fmaf(w, ss1[64 + m], acc);
        wB1f[n * 192 + m] = w * ss1[m];
    }
#pragma unroll
    for (int m = 0; m < 64; ++m) {
        float w = wB1f[n * 192 + 64 + m];
        acc = fmaf(w, ss2[64 + m], acc);
        wB1f[n * 192 + 64 + m] = w * ss2[m];
    }
    b1[n] += acc;
    __syncthreads();
    for (int j = n; j < 256 * 192; j += 256) wB1h[j] = f2bf(wB1f[j]);
}

// ---------------- MFMA 2-layer LSTM: 4 waves, weights in regs, 1 barrier/t ----------------
// hx1 AND hx2 double-buffered by t-parity: the only hazard needing a barrier is the
// RAW between pointwise-1's hx1 write and layer-2's MFMA read (same t). All cross-t
// WAR/RAW hazards are covered by that one collective barrier per iteration.
__global__ __launch_bounds__(256, 2) void k_lstm_mfma4(
    const ushort_t* __restrict__ h1bf, const ushort_t* __restrict__ h2bf,
    const ushort_t* __restrict__ wB1, const ushort_t* __restrict__ wB2,
    const float* __restrict__ bs1, const float* __restrict__ bs2,
    float* __restrict__ hA, float* __restrict__ hB) {
    __shared__ ushort_t hx1[2][1024], hx2[2][1024];   // XOR-swizzled, t-parity dbuf
    int tid = threadIdx.x;
    int lane = tid & 63, wv = tid >> 6;
    int c15 = lane & 15, g4 = lane >> 4;
    int g8 = g4 * 8;
    int bn0 = blockIdx.x * 16;
    int b = bn0 / NNODES, nn0 = bn0 - b * NNODES;

    for (int i = tid; i < 2048; i += 256) {
        if (i < 1024) ((uint_t*)hx1)[i] = 0u;
        else ((uint_t*)hx2)[i - 1024] = 0u;
    }

    s8v w1f[4][6], w2f[4][4];
#pragma unroll
    for (int j = 0; j < 4; ++j) {
        const ushort_t* base1 = wB1 + (size_t)((wv + 4 * j) * 16 + c15) * 192 + g8;
#pragma unroll
        for (int kk = 0; kk < 6; ++kk) w1f[j][kk] = *(const s8v*)(base1 + kk * 32);
        const ushort_t* base2 = wB2 + (size_t)((wv + 4 * j) * 16 + c15) * 128 + g8;
#pragma unroll
        for (int kk = 0; kk < 4; ++kk) w2f[j][kk] = *(const s8v*)(base2 + kk * 32);
    }
    float bi1[4], bi2[4];
#pragma unroll
    for (int j = 0; j < 4; ++j) {
        bi1[j] = bs1[(wv + 4 * j) * 16 + c15];
        bi2[j] = bs2[(wv + 4 * j) * 16 + c15];
    }
    float cA[4], cB[4];
#pragma unroll
    for (int q = 0; q < 4; ++q) { cA[q] = 0.f; cB[q] = 0.f; }

    int r7 = c15 & 7;
    int a_lo = c15 * 64 + ((g4 ^ r7) << 3);
    int a_hi = c15 * 64 + (((4 + g4) ^ r7) << 3);
    int u = wv * 16 + c15;
    int hxcol_hi = (u >> 3) << 3;
    int u7 = u & 7;

    __syncthreads();

    for (int t = 0; t < WINN; ++t) {
        int cur = t & 1, prv = 1 - cur;
        size_t node = (size_t)((b * WINN + t) * NNODES + nn0 + c15) * 64 + g8;
        s8v a[6];
        a[0] = *(const s8v*)(h1bf + node);
        a[1] = *(const s8v*)(h1bf + node + 32);
        a[2] = *(const s8v*)(h2bf + node);
        a[3] = *(const s8v*)(h2bf + node + 32);
        a[4] = *(const s8v*)(&hx1[prv][a_lo]);
        a[5] = *(const s8v*)(&hx1[prv][a_hi]);

        f4 acc[4];
#pragma unroll
        for (int j = 0; j < 4; ++j) { f4 v = {bi1[j], bi1[j], bi1[j], bi1[j]}; acc[j] = v; }
#pragma unroll
        for (int j = 0; j < 4; ++j)
#pragma unroll
            for (int kk = 0; kk < 6; ++kk)
                acc[j] = __builtin_amdgcn_mfma_f32_16x16x32_bf16(a[kk], w1f[j][kk], acc[j], 0, 0, 0);
#pragma unroll
        for (int q = 0; q < 4; ++q) {
            float ig = sigmoidf_(acc[0][q]);
            float fg = sigmoidf_(acc[1][q]);
            float gg = tanhf_(acc[2][q]);
            float og = sigmoidf_(acc[3][q]);
            float cv = fmaf(fg, cA[q], ig * gg);
            cA[q] = cv;
            float hv = og * tanhf_(cv);
            int rr = g4 * 4 + q;
            hx1[cur][rr * 64 + (hxcol_hi ^ ((rr & 7) << 3)) + u7] = f2bf(hv);
        }
        __syncthreads();   // hx1[cur] visible to all waves for layer 2

        s8v r[4];
        r[0] = *(const s8v*)(&hx1[cur][a_lo]);
        r[1] = *(const s8v*)(&hx1[cur][a_hi]);
        r[2] = *(const s8v*)(&hx2[prv][a_lo]);
        r[3] = *(const s8v*)(&hx2[prv][a_hi]);
#pragma unroll
        for (int j = 0; j < 4; ++j) { f4 v = {bi2[j], bi2[j], bi2[j], bi2[j]}; acc[j] = v; }
#pragma unroll
        for (int j = 0; j < 4; ++j)
#pragma unroll
            for (int kk = 0; kk < 4; ++kk)
                acc[j] = __builtin_amdgcn_mfma_f32_16x16x32_bf16(r[kk], w2f[j][kk], acc[j], 0, 0, 0);
#pragma unroll
        for (int q = 0; q < 4; ++q) {
            float ig = sigmoidf_(acc[0][q]);
            float fg = sigmoidf_(acc[1][q]);
            float gg = tanhf_(acc[2][q]);
            float og = sigmoidf_(acc[3][q]);
            float cv = fmaf(fg, cB[q], ig * gg);
            cB[q] = cv;
            float hv = og * tanhf_(cv);
            int rr = g4 * 4 + q;
            hx2[cur][rr * 64 + (hxcol_hi ^ ((rr & 7) << 3)) + u7] = f2bf(hv);
        }
        // hx2[cur] visibility for t+1's layer-2 is covered by t+1's barrier
    }
    __syncthreads();
    int fin = (WINN - 1) & 1;
    for (int i = tid; i < 1024; i += 256) {
        int rr = i >> 6, uu = i & 63;
        int hw2 = rr * 64 + ((((uu >> 3) ^ (rr & 7)) << 3)) + (uu & 7);
        hA[(size_t)(bn0 + rr) * 64 + uu] = bf2f(hx1[fin][hw2]);
        hB[(size_t)(bn0 + rr) * 64 + uu] = bf2f(hx2[fin][hw2]);
    }
}

// head: z = relu([hn1|hn2|skip] @ fc1^T + b1); out = relu(z @ fc2^T + b2)
__global__ void k_head(const float* __restrict__ hA, const float* __restrict__ hB,
                       const float* __restrict__ x, const float* __restrict__ fc1T,
                       const float* __restrict__ fc1b, const float* __restrict__ fc2w,
                       const float* __restrict__ fc2b, float* __restrict__ out) {
    int lane = threadIdx.x & 63, wv = threadIdx.x >> 6;
    int bn = blockIdx.x * 4 + wv;
    __shared__ float sz[4][208];
    int b = bn / NNODES, nn = bn - b * NNODES;
    for (int k = lane; k < 208; k += 64) {
        float v;
        if (k < 64) v = hA[(size_t)bn * 64 + k];
        else if (k < 128) v = hB[(size_t)bn * 64 + (k - 64)];
        else {
            int kk = k - 128;
            int w = kk >> 3, f = kk & 7;
            v = x[(size_t)((b * WINN + w) * NNODES + nn) * NFEAT + f];
        }
        sz[wv][k] = v;
    }
    __syncthreads();
    float acc = fc1b[lane];
    for (int k = 0; k < 208; ++k) acc = fmaf(sz[wv][k], fc1T[k * 64 + lane], acc);
    acc = acc > 0.f ? acc : 0.f;
    float v = acc * fc2w[lane];
#pragma unroll
    for (int m = 32; m >= 1; m >>= 1) v += __shfl_xor(v, m, 64);
    if (lane == 0) {
        float z = v + fc2b[0];
        out[bn] = z > 0.f ? z : 0.f;
    }
}

// ---------------- launch ----------------
extern "C" void kernel_launch(void* const* d_in, const int* in_sizes, int n_in,
                              void* d_out, int out_size, void* d_ws, size_t ws_size,
                              hipStream_t stream) {
    const float* x     = (const float*)d_in[0];
    const int*   ei    = (const int*)d_in[1];
    const float* ew    = (const float*)d_in[2];
    const float* c1w   = (const float*)d_in[3];
    const float* c1b   = (const float*)d_in[4];
    const float* c2w   = (const float*)d_in[5];
    const float* c2b   = (const float*)d_in[6];
    const float* bn1g  = (const float*)d_in[7];
    const float* bn1b  = (const float*)d_in[8];
    const float* bn2g  = (const float*)d_in[9];
    const float* bn2b  = (const float*)d_in[10];
    const float* wih1  = (const float*)d_in[11];
    const float* whh1  = (const float*)d_in[12];
    const float* bih1  = (const float*)d_in[13];
    const float* bhh1  = (const float*)d_in[14];
    const float* wih2  = (const float*)d_in[15];
    const float* whh2  = (const float*)d_in[16];
    const float* bih2  = (const float*)d_in[17];
    const float* bhh2  = (const float*)d_in[18];
    const float* fc1w  = (const float*)d_in[19];
    const float* fc1b  = (const float*)d_in[20];
    const float* fc2w  = (const float*)d_in[21];
    const float* fc2b  = (const float*)d_in[22];
    float* out = (float*)d_out;

    float* ws = (float*)d_ws;
    size_t off = 0;
    auto A = [&](size_t n) { float* p = ws + off; off += n; return p; };
    float* dinv   = A(NTOT);
    float* aggX   = A((size_t)NTOT * NFEAT);
    ushort_t* h1bf = (ushort_t*)A((size_t)NTOT * 32);   // r = relu(gcn1), pre-BN, bf16
    ushort_t* h2bf = (ushort_t*)A((size_t)NTOT * 32);   // relu(gcn2), pre-BN2, bf16
    ushort_t* gbuf = (ushort_t*)A((size_t)NTOT * 32);   // post-BN1 aggregate, bf16

    // union: CSR (GCN phase) aliases final LSTM states (LSTM/head phase)
    size_t uoff = off;
    float* hA = A((size_t)NBN * 64);
    float* hB = A((size_t)NBN * 64);
    A(2 * (size_t)NEDGE + (NTOT + 1) + 8 * (size_t)NTOT - 2 * (size_t)NBN * 64);
    int2* epack = (int2*)(ws + uoff);
    int*  ptr   = (int*)(epack + NEDGE);        // NTOT+1
    int*  cntP  = ptr + NTOT + 1;               // 8*NTOT (hist, then cursors)

    float* wB1f = A(256 * 192);
    ushort_t* wB1h = (ushort_t*)A(256 * 96);
    ushort_t* wB2h = (ushort_t*)A(256 * 64);
    float* b1   = A(256);
    float* b2   = A(256);
    float* fc1T = A(208 * 64);
    float* sums = A(2048);
    float* ss1  = A(128);
    float* ss2  = A(128);
    float* scanTmpF = A(512);
    int* scanTmp = (int*)scanTmpF;
    // total ~52.2M floats = 209 MB < 256 MiB

    if (ws_size < off * sizeof(float)) {
        k_diag<<<(out_size + 255) / 256, 256, 0, stream>>>(out, (float)ws_size, out_size);
        return;
    }

    constexpr int SCAN_NB = (NTOT + 1023) / 1024;

    // CSR build
    k_init<<<8 * NTOT / 256, 256, 0, stream>>>(cntP, sums);
    k_hist<<<NEDGE / 256, 256, 0, stream>>>(ei, cntP);
    k_scan1<<<SCAN_NB, 256, 0, stream>>>(cntP, ptr, scanTmp);
    k_scan2<<<1, 512, 0, stream>>>(scanTmp, SCAN_NB);
    k_scan3<<<(NTOT + 255) / 256, 256, 0, stream>>>(ptr, cntP, scanTmp);
    k_fill<<<NEDGE / 256, 256, 0, stream>>>(ei, ew, cntP, epack);
    k_degcsr<<<NTOT / 8 / 4, 256, 0, stream>>>(ptr, epack, dinv);
    k_prep<<<192, 256, 0, stream>>>(wih1, whh1, bih1, bhh1, wih2, whh2, bih2, bhh2,
                                    fc1w, wB1f, b1, wB2h, b2, fc1T);

    // ---- GCN layer 1 (BN1 never materialized: stats only) ----
    k_gather8<<<NTOT / 8 / 4, 256, 0, stream>>>(ptr, epack, x, dinv, aggX);
    k_lin1<<<512, 256, 0, stream>>>(aggX, c1w, c1b, h1bf, sums);
    k_bn_final<<<1, 64, 0, stream>>>(sums, bn1g, bn1b, ss1);

    // ---- GCN layer 2: one-wave-per-node gather (BN1 inline, bf16 out), then GEMV ----
    k_gather64b<<<NTOT / 4, 256, 0, stream>>>(ptr, epack, h1bf, dinv, ss1, gbuf);
    k_lin2c<<<2048, 256, 0, stream>>>(gbuf, c2w, c2b, h2bf, sums + 128);
    k_bn_final8<<<1, 64, 0, stream>>>(sums + 128, bn2g, bn2b, ss2);
    k_fold2<<<1, 256, 0, stream>>>(wB1f, b1, ss1, ss2, wB1h);

    // ---- MFMA LSTM: weights in VGPRs, 1 barrier/t ----
    k_lstm_mfma4<<<NBN / 16, 256, 0, stream>>>(h1bf, h2bf, wB1h, wB2h, b1, b2, hA, hB);

    // ---- head ----
    k_head<<<NBN / 4, 256, 0, stream>>>(hA, hB, x, fc1T, fc1b, fc2w, fc2b, out);
}